// Round 7
// baseline (400.179 us; speedup 1.0000x reference)
//
#include <hip/hip_runtime.h>
#include <hip/hip_bf16.h>
#include <math.h>

// ChebyNet: 2-layer ChebConv (K=4), N=100000, E=1600000, F 32->16->10, log_softmax.
//
// R7: make every gather table fit one XCD's 4MB L2 (3.2MB = N x 32B rows):
//   - layer-2 tables (h, S1..S3) stored bf16 (16 feats = 32B row)
//   - layer-1 props split into lo/hi 16-feature halves (two passes over the
//     edge stream, each gathering from a 3.2MB half-table)
// One kernel (prop_b16x2) serves both: rows = 2 x uint4 chunks, 2 lanes/node,
// fp32 accumulate, bf16 store, Cheby recurrence folded into epilogue.
// CSR build unchanged (R5): bucket_count/scan -> binned_scatter -> bucket_place.
// norm folded: out[n] = -dis[n] * sum dis[s]*v[s].

#define BLK 256
#define BLKP 512
#define NBUCK_MAX 256   // buckets = ceil(N/512); requires N <= 131072
#define CHUNK 8192      // edges per binned_scatter block
#define PLACE_CAP 10240 // staging capacity in bucket_place (avg bucket = 8192)

// ---------- bf16 helpers (storage-only quantization) ----------
__device__ inline unsigned short f32_to_bf16_rne(float f) {
    unsigned int u = __float_as_uint(f);
    unsigned int rounding = 0x7FFFu + ((u >> 16) & 1u);
    return (unsigned short)((u + rounding) >> 16);
}
__device__ inline unsigned int pack_bf16x2(float a, float b) {
    return (unsigned int)f32_to_bf16_rne(a) | ((unsigned int)f32_to_bf16_rne(b) << 16);
}
__device__ inline void unpack8(const uint4 u, float* f) {
    const unsigned int* p = &u.x;
#pragma unroll
    for (int j = 0; j < 4; j++) {
        unsigned int w = p[j];
        f[2 * j]     = __uint_as_float(w << 16);
        f[2 * j + 1] = __uint_as_float(w & 0xFFFF0000u);
    }
}
__device__ inline void fma8(const uint4 u, float wgt, float* acc) {
    const unsigned int* p = &u.x;
#pragma unroll
    for (int j = 0; j < 4; j++) {
        unsigned int w = p[j];
        acc[2 * j]     += wgt * __uint_as_float(w << 16);
        acc[2 * j + 1] += wgt * __uint_as_float(w & 0xFFFF0000u);
    }
}
__device__ inline uint4 pack8(const float* r) {
    uint4 o;
    o.x = pack_bf16x2(r[0], r[1]);
    o.y = pack_bf16x2(r[2], r[3]);
    o.z = pack_bf16x2(r[4], r[5]);
    o.w = pack_bf16x2(r[6], r[7]);
    return o;
}

// fp32 x [N,32] -> bf16 half-tables xlo (feats 0..15), xhi (16..31), 32B rows
__global__ void cvt_split_kernel(const float* __restrict__ x, uint4* __restrict__ xlo,
                                 uint4* __restrict__ xhi, int N) {
    int t = blockIdx.x * blockDim.x + threadIdx.x;  // one 16B chunk (8 feats)
    if (t >= N * 4) return;
    int n = t >> 2;
    int q = t & 3;               // q: 0,1 -> lo; 2,3 -> hi
    const float4* in4 = reinterpret_cast<const float4*>(x + (size_t)n * 32 + q * 8);
    float4 a = in4[0], b = in4[1];
    float r[8] = {a.x, a.y, a.z, a.w, b.x, b.y, b.z, b.w};
    uint4* dst = (q < 2) ? xlo : xhi;
    dst[(size_t)n * 2 + (q & 1)] = pack8(r);
}

// ---------- CSR build (unchanged from R5) ----------
__global__ void bucket_count_kernel(const int* __restrict__ dst, int* __restrict__ bcnt,
                                    int E, int nbuck) {
    __shared__ int cnt[NBUCK_MAX];
    for (int b = threadIdx.x; b < NBUCK_MAX; b += BLK) cnt[b] = 0;
    __syncthreads();
    int t = blockIdx.x * BLK + threadIdx.x;
    int stride = gridDim.x * BLK;
    int E4 = E >> 2;
    for (int i = t; i < E4; i += stride) {
        int4 d = *reinterpret_cast<const int4*>(dst + i * 4);
        atomicAdd(&cnt[d.x >> 9], 1);
        atomicAdd(&cnt[d.y >> 9], 1);
        atomicAdd(&cnt[d.z >> 9], 1);
        atomicAdd(&cnt[d.w >> 9], 1);
    }
    if (t == 0) for (int j = E4 * 4; j < E; j++) atomicAdd(&bcnt[dst[j] >> 9], 1);
    __syncthreads();
    for (int b = threadIdx.x; b < nbuck; b += BLK)
        if (cnt[b]) atomicAdd(&bcnt[b], cnt[b]);
}

__global__ void bucket_scan_kernel(const int* __restrict__ bcnt, int* __restrict__ bbase,
                                   int* __restrict__ bfill, int* __restrict__ rowptr,
                                   int nbuck, int N, int E) {
    __shared__ int sh[NBUCK_MAX];
    int tid = threadIdx.x;
    int v = (tid < nbuck) ? bcnt[tid] : 0;
    sh[tid] = v;
    __syncthreads();
    for (int off = 1; off < BLK; off <<= 1) {
        int t = (tid >= off) ? sh[tid - off] : 0;
        __syncthreads();
        sh[tid] += t;
        __syncthreads();
    }
    if (tid < nbuck) bbase[tid] = sh[tid] - v;
    bfill[tid] = 0;
    if (tid == 0) { bbase[nbuck] = E; rowptr[N] = E; }
}

__global__ void binned_scatter_kernel(const int* __restrict__ src, const int* __restrict__ dst,
                                      const int* __restrict__ bbase, int* __restrict__ bfill,
                                      int* __restrict__ tmp, int E, int nbuck) {
    __shared__ int cnt[NBUCK_MAX];
    __shared__ int lofs[NBUCK_MAX + 1];
    __shared__ int pos[NBUCK_MAX];
    __shared__ int gbase[NBUCK_MAX];
    __shared__ int stage[CHUNK];
    __shared__ unsigned char bkt[CHUNK];

    int tid = threadIdx.x;
    int e0 = blockIdx.x * CHUNK;
    int nE = min(CHUNK, E - e0);

    for (int b = tid; b < nbuck; b += BLK) { cnt[b] = 0; pos[b] = 0; }
    __syncthreads();

    for (int i = tid; i < nE; i += BLK) {
        int d = dst[e0 + i];
        atomicAdd(&cnt[d >> 9], 1);
    }
    __syncthreads();

    {
        int v = (tid < nbuck) ? cnt[tid] : 0;
        lofs[tid] = v;
        __syncthreads();
        for (int off = 1; off < BLK; off <<= 1) {
            int t = (tid >= off) ? lofs[tid - off] : 0;
            __syncthreads();
            lofs[tid] += t;
            __syncthreads();
        }
        int incl = lofs[tid];
        __syncthreads();
        lofs[tid] = incl - v;
        if (tid == 0) lofs[nbuck] = nE;
        if (tid < nbuck && v > 0)
            gbase[tid] = bbase[tid] + atomicAdd(&bfill[tid], v);
    }
    __syncthreads();

    for (int i = tid; i < nE; i += BLK) {
        int s = src[e0 + i];
        int d = dst[e0 + i];
        int b = d >> 9;
        int slot = lofs[b] + atomicAdd(&pos[b], 1);
        stage[slot] = (s << 9) | (d & 511);
        bkt[slot] = (unsigned char)b;
    }
    __syncthreads();

    for (int i = tid; i < nE; i += BLK) {
        int b = bkt[i];
        tmp[gbase[b] + (i - lofs[b])] = stage[i];
    }
}

__global__ void bucket_place_kernel(const int* __restrict__ bbase, const int* __restrict__ tmp,
                                    int* __restrict__ psrc, int* __restrict__ rowptr,
                                    float* __restrict__ dis, int N) {
    __shared__ int cnt[512];
    __shared__ int ofs[512];
    __shared__ int fill[512];
    __shared__ int stage[PLACE_CAP];

    int b = blockIdx.x;
    int tid = threadIdx.x;
    int n0 = b << 9;
    int nn = min(512, N - n0);
    int S = bbase[b];
    int tot = bbase[b + 1] - S;

    cnt[tid] = 0;
    fill[tid] = 0;
    __syncthreads();

    for (int i = tid; i < tot; i += BLKP) atomicAdd(&cnt[tmp[S + i] & 511], 1);
    __syncthreads();

    int v = cnt[tid];
    ofs[tid] = v;
    __syncthreads();
    for (int off = 1; off < 512; off <<= 1) {
        int t = (tid >= off) ? ofs[tid - off] : 0;
        __syncthreads();
        ofs[tid] += t;
        __syncthreads();
    }
    int excl = ofs[tid] - v;
    __syncthreads();
    ofs[tid] = excl;
    if (tid < nn) {
        rowptr[n0 + tid] = S + excl;
        dis[n0 + tid] = (v > 0) ? rsqrtf((float)v) : 0.0f;
    }
    __syncthreads();

    if (tot <= PLACE_CAP) {
        for (int i = tid; i < tot; i += BLKP) {
            int rec = tmp[S + i];
            int nl = rec & 511;
            int slot = ofs[nl] + atomicAdd(&fill[nl], 1);
            stage[slot] = rec >> 9;
        }
        __syncthreads();
        for (int i = tid; i < tot; i += BLKP) psrc[S + i] = stage[i];
    } else {
        for (int i = tid; i < tot; i += BLKP) {
            int rec = tmp[S + i];
            int nl = rec & 511;
            int slot = S + ofs[nl] + atomicAdd(&fill[nl], 1);
            psrc[slot] = rec >> 9;
        }
    }
}

// ---------- unified prop: bf16 32B rows (2 x uint4 chunks), 2 lanes/node ----------
// out[n] = (-scale*dis[n]) * sum_{e} dis[src]*v[src]  (- prev[n] if HAVE_PREV)
template <bool HAVE_PREV>
__global__ void prop_b16x2_kernel(const int* __restrict__ rowptr, const int* __restrict__ psrc,
                                  const float* __restrict__ dis, const uint4* __restrict__ vb,
                                  const uint4* __restrict__ prevb, uint4* __restrict__ outb,
                                  float scale, int N) {
    int t = blockIdx.x * blockDim.x + threadIdx.x;
    int n = t >> 1;
    int c = t & 1;
    if (n >= N) return;
    int beg = rowptr[n];
    int end = rowptr[n + 1];
    float acc[8];
#pragma unroll
    for (int j = 0; j < 8; j++) acc[j] = 0.f;
    int i = beg;
    for (; i + 3 < end; i += 4) {
        int s0 = psrc[i], s1 = psrc[i + 1], s2 = psrc[i + 2], s3 = psrc[i + 3];
        uint4 a0 = vb[(size_t)s0 * 2 + c];
        uint4 a1 = vb[(size_t)s1 * 2 + c];
        uint4 a2 = vb[(size_t)s2 * 2 + c];
        uint4 a3 = vb[(size_t)s3 * 2 + c];
        float w0 = dis[s0], w1 = dis[s1], w2 = dis[s2], w3 = dis[s3];
        fma8(a0, w0, acc);
        fma8(a1, w1, acc);
        fma8(a2, w2, acc);
        fma8(a3, w3, acc);
    }
    for (; i < end; i++) {
        int s0 = psrc[i];
        uint4 a0 = vb[(size_t)s0 * 2 + c];
        fma8(a0, dis[s0], acc);
    }
    float dn = -scale * dis[n];
    float r[8];
    if (HAVE_PREV) {
        float p[8];
        unpack8(prevb[(size_t)n * 2 + c], p);
#pragma unroll
        for (int j = 0; j < 8; j++) r[j] = dn * acc[j] - p[j];
    } else {
#pragma unroll
        for (int j = 0; j < 8; j++) r[j] = dn * acc[j];
    }
    outb[(size_t)n * 2 + c] = pack8(r);
}

// h = relu(b1 + sum_k Txk@W1[k]); inputs are bf16 half-tables; h stored bf16 (32B row)
__global__ void combine1_kernel(const uint4* __restrict__ xlo, const uint4* __restrict__ xhi,
                                const uint4* __restrict__ t1lo, const uint4* __restrict__ t1hi,
                                const uint4* __restrict__ t2lo, const uint4* __restrict__ t2hi,
                                const uint4* __restrict__ t3lo, const uint4* __restrict__ t3hi,
                                const float* __restrict__ W1, const float* __restrict__ b1,
                                uint4* __restrict__ hb, int N) {
    __shared__ float sW[4 * 32 * 16];
    __shared__ float sb[16];
    for (int i = threadIdx.x; i < 4 * 32 * 16; i += blockDim.x) sW[i] = W1[i];
    if (threadIdx.x < 16) sb[threadIdx.x] = b1[threadIdx.x];
    __syncthreads();
    int n = blockIdx.x * blockDim.x + threadIdx.x;
    if (n >= N) return;
    float acc[16];
#pragma unroll
    for (int j = 0; j < 16; j++) acc[j] = sb[j];
    const uint4* lo[4] = {xlo, t1lo, t2lo, t3lo};
    const uint4* hi[4] = {xhi, t1hi, t2hi, t3hi};
#pragma unroll
    for (int k = 0; k < 4; k++) {
        float row[32];
        unpack8(lo[k][(size_t)n * 2 + 0], row + 0);
        unpack8(lo[k][(size_t)n * 2 + 1], row + 8);
        unpack8(hi[k][(size_t)n * 2 + 0], row + 16);
        unpack8(hi[k][(size_t)n * 2 + 1], row + 24);
        const float* Wk = sW + k * 512;
#pragma unroll
        for (int i = 0; i < 32; i++) {
            float xv = row[i];
#pragma unroll
            for (int j = 0; j < 16; j++) acc[j] += xv * Wk[i * 16 + j];
        }
    }
    float r[16];
#pragma unroll
    for (int j = 0; j < 16; j++) r[j] = fmaxf(acc[j], 0.0f);
    hb[(size_t)n * 2 + 0] = pack8(r);
    hb[(size_t)n * 2 + 1] = pack8(r + 8);
}

// o = log_softmax(b2 + sum_k Sk@W2[k]); Sk are bf16 32B rows; output fp32
__global__ void combine2_kernel(const uint4* __restrict__ hb, const uint4* __restrict__ s1,
                                const uint4* __restrict__ s2, const uint4* __restrict__ s3,
                                const float* __restrict__ W2, const float* __restrict__ b2,
                                float* __restrict__ out, int N) {
    __shared__ float sW[4 * 16 * 10];
    __shared__ float sb[10];
    for (int i = threadIdx.x; i < 4 * 16 * 10; i += blockDim.x) sW[i] = W2[i];
    if (threadIdx.x < 10) sb[threadIdx.x] = b2[threadIdx.x];
    __syncthreads();
    int n = blockIdx.x * blockDim.x + threadIdx.x;
    if (n >= N) return;
    float acc[10];
#pragma unroll
    for (int c = 0; c < 10; c++) acc[c] = sb[c];
    const uint4* tabs[4] = {hb, s1, s2, s3};
#pragma unroll
    for (int k = 0; k < 4; k++) {
        float row[16];
        unpack8(tabs[k][(size_t)n * 2 + 0], row + 0);
        unpack8(tabs[k][(size_t)n * 2 + 1], row + 8);
        const float* Wk = sW + k * 160;
#pragma unroll
        for (int i = 0; i < 16; i++) {
            float xv = row[i];
#pragma unroll
            for (int c = 0; c < 10; c++) acc[c] += xv * Wk[i * 10 + c];
        }
    }
    float m = acc[0];
#pragma unroll
    for (int c = 1; c < 10; c++) m = fmaxf(m, acc[c]);
    float sum = 0.0f;
#pragma unroll
    for (int c = 0; c < 10; c++) sum += expf(acc[c] - m);
    float lse = m + logf(sum);
    float* o = out + (size_t)n * 10;
#pragma unroll
    for (int c = 0; c < 10; c++) o[c] = acc[c] - lse;
}

extern "C" void kernel_launch(void* const* d_in, const int* in_sizes, int n_in,
                              void* d_out, int out_size, void* d_ws, size_t ws_size,
                              hipStream_t stream) {
    const float* x  = (const float*)d_in[0];
    const int*   ei = (const int*)d_in[1];
    const float* W1 = (const float*)d_in[2];
    const float* b1 = (const float*)d_in[3];
    const float* W2 = (const float*)d_in[4];
    const float* b2 = (const float*)d_in[5];
    float* out = (float*)d_out;

    const int N = in_sizes[0] / 32;   // 100000
    const int E = in_sizes[1] / 2;    // 1600000
    const int* src = ei;
    const int* dst = ei + E;

    const int nbuck = (N + 511) / 512;        // 196

    // workspace layout (16B-aligned regions); bf16 tables are N x 32B
    char* w = (char*)d_ws;
    int*   bcnt   = (int*)w;              w += NBUCK_MAX * 4;
    int*   bbase  = (int*)w;              w += (NBUCK_MAX + 4) * 4;
    int*   bfill  = (int*)w;              w += NBUCK_MAX * 4;
    int*   rowptr = (int*)w;              w += (size_t)(N + 4) * 4;
    float* dis    = (float*)w;            w += (size_t)N * 4;
    int*   tmp    = (int*)w;              w += (size_t)E * 4;
    int*   psrc   = (int*)w;              w += (size_t)E * 4;
    uint4* xlo    = (uint4*)w;            w += (size_t)32 * N;
    uint4* xhi    = (uint4*)w;            w += (size_t)32 * N;
    uint4* t1lo   = (uint4*)w;            w += (size_t)32 * N;
    uint4* t1hi   = (uint4*)w;            w += (size_t)32 * N;
    uint4* t2lo   = (uint4*)w;            w += (size_t)32 * N;
    uint4* t2hi   = (uint4*)w;            w += (size_t)32 * N;
    uint4* t3lo   = (uint4*)w;            w += (size_t)32 * N;
    uint4* t3hi   = (uint4*)w;            w += (size_t)32 * N;
    uint4* hb     = (uint4*)w;            w += (size_t)32 * N;
    uint4* s1     = (uint4*)w;            w += (size_t)32 * N;
    uint4* s2     = (uint4*)w;            w += (size_t)32 * N;
    uint4* s3     = (uint4*)w;            w += (size_t)32 * N;

    int gN   = (N + BLK - 1) / BLK;
    int gB2  = (N * 2 + BLK - 1) / BLK;   // 2 lanes/node
    int gCVT = (N * 4 + BLK - 1) / BLK;
    int gCH  = (E + CHUNK - 1) / CHUNK;

    // ---- CSR build ----
    hipMemsetAsync(bcnt, 0, NBUCK_MAX * sizeof(int), stream);
    bucket_count_kernel<<<1024, BLK, 0, stream>>>(dst, bcnt, E, nbuck);
    bucket_scan_kernel<<<1, BLK, 0, stream>>>(bcnt, bbase, bfill, rowptr, nbuck, N, E);
    binned_scatter_kernel<<<gCH, BLK, 0, stream>>>(src, dst, bbase, bfill, tmp, E, nbuck);
    bucket_place_kernel<<<nbuck, BLKP, 0, stream>>>(bbase, tmp, psrc, rowptr, dis, N);

    // ---- layer 1 (F=32 as lo/hi 16-feat halves, bf16, 3.2MB tables) ----
    cvt_split_kernel<<<gCVT, BLK, 0, stream>>>(x, xlo, xhi, N);
    prop_b16x2_kernel<false><<<gB2, BLK, 0, stream>>>(rowptr, psrc, dis, xlo,  nullptr, t1lo, 1.0f, N);
    prop_b16x2_kernel<false><<<gB2, BLK, 0, stream>>>(rowptr, psrc, dis, xhi,  nullptr, t1hi, 1.0f, N);
    prop_b16x2_kernel<true ><<<gB2, BLK, 0, stream>>>(rowptr, psrc, dis, t1lo, xlo,     t2lo, 2.0f, N);
    prop_b16x2_kernel<true ><<<gB2, BLK, 0, stream>>>(rowptr, psrc, dis, t1hi, xhi,     t2hi, 2.0f, N);
    prop_b16x2_kernel<true ><<<gB2, BLK, 0, stream>>>(rowptr, psrc, dis, t2lo, t1lo,    t3lo, 2.0f, N);
    prop_b16x2_kernel<true ><<<gB2, BLK, 0, stream>>>(rowptr, psrc, dis, t2hi, t1hi,    t3hi, 2.0f, N);
    combine1_kernel<<<gN, BLK, 0, stream>>>(xlo, xhi, t1lo, t1hi, t2lo, t2hi, t3lo, t3hi,
                                            W1, b1, hb, N);

    // ---- layer 2 (F=16, bf16, 3.2MB tables) ----
    prop_b16x2_kernel<false><<<gB2, BLK, 0, stream>>>(rowptr, psrc, dis, hb, nullptr, s1, 1.0f, N);
    prop_b16x2_kernel<true ><<<gB2, BLK, 0, stream>>>(rowptr, psrc, dis, s1, hb,      s2, 2.0f, N);
    prop_b16x2_kernel<true ><<<gB2, BLK, 0, stream>>>(rowptr, psrc, dis, s2, s1,      s3, 2.0f, N);
    combine2_kernel<<<gN, BLK, 0, stream>>>(hb, s1, s2, s3, W2, b2, out, N);
}

// Round 8
// 355.728 us; speedup vs baseline: 1.1250x; 1.1250x over previous
//
#include <hip/hip_runtime.h>
#include <hip/hip_bf16.h>
#include <math.h>

// ChebyNet: 2-layer ChebConv (K=4), N=100000, E=1600000, F 32->16->10, log_softmax.
//
// R8: revert R7's feature-split (two edge-stream passes per stage cost more
// than 3.2MB-table L2 residency gained; 370->400 regression). Back to R6's
// single-pass full-row L1 prop (64B bf16 rows, 4 lanes/node) + keep bf16
// layer-2 tables (32B rows, 2 lanes/node). NEW: U-space recurrence
// U_k[n] = dis[n]*Tx_k[n] -- props become pure gather-SUMS (no per-edge
// dis[src] gather), epilogue U_{k+1} = -scale*d2[n]*acc - U_{k-1}.
// Combines recover Tx_k = U_k * inv[n] (inv = sqrt(deg)); deg-0 nodes get
// exact fallback (Tx2=-x / S2=-h). CSR build unchanged (R5).

#define BLK 256
#define BLKP 512
#define NBUCK_MAX 256   // buckets = ceil(N/512); requires N <= 131072
#define CHUNK 8192      // edges per binned_scatter block
#define PLACE_CAP 10240 // staging capacity in bucket_place (avg bucket = 8192)

// ---------- bf16 helpers (storage-only quantization) ----------
__device__ inline unsigned short f32_to_bf16_rne(float f) {
    unsigned int u = __float_as_uint(f);
    unsigned int rounding = 0x7FFFu + ((u >> 16) & 1u);
    return (unsigned short)((u + rounding) >> 16);
}
__device__ inline unsigned int pack_bf16x2(float a, float b) {
    return (unsigned int)f32_to_bf16_rne(a) | ((unsigned int)f32_to_bf16_rne(b) << 16);
}
__device__ inline void unpack8(const uint4 u, float* f) {
    const unsigned int* p = &u.x;
#pragma unroll
    for (int j = 0; j < 4; j++) {
        unsigned int w = p[j];
        f[2 * j]     = __uint_as_float(w << 16);
        f[2 * j + 1] = __uint_as_float(w & 0xFFFF0000u);
    }
}
__device__ inline void add8(const uint4 u, float* acc) {
    const unsigned int* p = &u.x;
#pragma unroll
    for (int j = 0; j < 4; j++) {
        unsigned int w = p[j];
        acc[2 * j]     += __uint_as_float(w << 16);
        acc[2 * j + 1] += __uint_as_float(w & 0xFFFF0000u);
    }
}
__device__ inline uint4 pack8(const float* r) {
    uint4 o;
    o.x = pack_bf16x2(r[0], r[1]);
    o.y = pack_bf16x2(r[2], r[3]);
    o.z = pack_bf16x2(r[4], r[5]);
    o.w = pack_bf16x2(r[6], r[7]);
    return o;
}

// ---------- CSR build ----------
__global__ void bucket_count_kernel(const int* __restrict__ dst, int* __restrict__ bcnt,
                                    int E, int nbuck) {
    __shared__ int cnt[NBUCK_MAX];
    for (int b = threadIdx.x; b < NBUCK_MAX; b += BLK) cnt[b] = 0;
    __syncthreads();
    int t = blockIdx.x * BLK + threadIdx.x;
    int stride = gridDim.x * BLK;
    int E4 = E >> 2;
    for (int i = t; i < E4; i += stride) {
        int4 d = *reinterpret_cast<const int4*>(dst + i * 4);
        atomicAdd(&cnt[d.x >> 9], 1);
        atomicAdd(&cnt[d.y >> 9], 1);
        atomicAdd(&cnt[d.z >> 9], 1);
        atomicAdd(&cnt[d.w >> 9], 1);
    }
    if (t == 0) for (int j = E4 * 4; j < E; j++) atomicAdd(&bcnt[dst[j] >> 9], 1);
    __syncthreads();
    for (int b = threadIdx.x; b < nbuck; b += BLK)
        if (cnt[b]) atomicAdd(&bcnt[b], cnt[b]);
}

__global__ void bucket_scan_kernel(const int* __restrict__ bcnt, int* __restrict__ bbase,
                                   int* __restrict__ bfill, int* __restrict__ rowptr,
                                   int nbuck, int N, int E) {
    __shared__ int sh[NBUCK_MAX];
    int tid = threadIdx.x;
    int v = (tid < nbuck) ? bcnt[tid] : 0;
    sh[tid] = v;
    __syncthreads();
    for (int off = 1; off < BLK; off <<= 1) {
        int t = (tid >= off) ? sh[tid - off] : 0;
        __syncthreads();
        sh[tid] += t;
        __syncthreads();
    }
    if (tid < nbuck) bbase[tid] = sh[tid] - v;
    bfill[tid] = 0;
    if (tid == 0) { bbase[nbuck] = E; rowptr[N] = E; }
}

__global__ void binned_scatter_kernel(const int* __restrict__ src, const int* __restrict__ dst,
                                      const int* __restrict__ bbase, int* __restrict__ bfill,
                                      int* __restrict__ tmp, int E, int nbuck) {
    __shared__ int cnt[NBUCK_MAX];
    __shared__ int lofs[NBUCK_MAX + 1];
    __shared__ int pos[NBUCK_MAX];
    __shared__ int gbase[NBUCK_MAX];
    __shared__ int stage[CHUNK];
    __shared__ unsigned char bkt[CHUNK];

    int tid = threadIdx.x;
    int e0 = blockIdx.x * CHUNK;
    int nE = min(CHUNK, E - e0);

    for (int b = tid; b < nbuck; b += BLK) { cnt[b] = 0; pos[b] = 0; }
    __syncthreads();

    for (int i = tid; i < nE; i += BLK) {
        int d = dst[e0 + i];
        atomicAdd(&cnt[d >> 9], 1);
    }
    __syncthreads();

    {
        int v = (tid < nbuck) ? cnt[tid] : 0;
        lofs[tid] = v;
        __syncthreads();
        for (int off = 1; off < BLK; off <<= 1) {
            int t = (tid >= off) ? lofs[tid - off] : 0;
            __syncthreads();
            lofs[tid] += t;
            __syncthreads();
        }
        int incl = lofs[tid];
        __syncthreads();
        lofs[tid] = incl - v;
        if (tid == 0) lofs[nbuck] = nE;
        if (tid < nbuck && v > 0)
            gbase[tid] = bbase[tid] + atomicAdd(&bfill[tid], v);
    }
    __syncthreads();

    for (int i = tid; i < nE; i += BLK) {
        int s = src[e0 + i];
        int d = dst[e0 + i];
        int b = d >> 9;
        int slot = lofs[b] + atomicAdd(&pos[b], 1);
        stage[slot] = (s << 9) | (d & 511);
        bkt[slot] = (unsigned char)b;
    }
    __syncthreads();

    for (int i = tid; i < nE; i += BLK) {
        int b = bkt[i];
        tmp[gbase[b] + (i - lofs[b])] = stage[i];
    }
}

// Phase 2: rank+place into psrc; also emit dis (1/sqrt(deg)), d2 (1/deg), inv (sqrt(deg))
__global__ void bucket_place_kernel(const int* __restrict__ bbase, const int* __restrict__ tmp,
                                    int* __restrict__ psrc, int* __restrict__ rowptr,
                                    float* __restrict__ dis, float* __restrict__ d2,
                                    float* __restrict__ inv, int N) {
    __shared__ int cnt[512];
    __shared__ int ofs[512];
    __shared__ int fill[512];
    __shared__ int stage[PLACE_CAP];

    int b = blockIdx.x;
    int tid = threadIdx.x;
    int n0 = b << 9;
    int nn = min(512, N - n0);
    int S = bbase[b];
    int tot = bbase[b + 1] - S;

    cnt[tid] = 0;
    fill[tid] = 0;
    __syncthreads();

    for (int i = tid; i < tot; i += BLKP) atomicAdd(&cnt[tmp[S + i] & 511], 1);
    __syncthreads();

    int v = cnt[tid];
    ofs[tid] = v;
    __syncthreads();
    for (int off = 1; off < 512; off <<= 1) {
        int t = (tid >= off) ? ofs[tid - off] : 0;
        __syncthreads();
        ofs[tid] += t;
        __syncthreads();
    }
    int excl = ofs[tid] - v;
    __syncthreads();
    ofs[tid] = excl;
    if (tid < nn) {
        rowptr[n0 + tid] = S + excl;
        float fv = (float)v;
        dis[n0 + tid] = (v > 0) ? rsqrtf(fv) : 0.0f;
        d2[n0 + tid]  = (v > 0) ? 1.0f / fv : 0.0f;
        inv[n0 + tid] = (v > 0) ? sqrtf(fv) : 0.0f;
    }
    __syncthreads();

    if (tot <= PLACE_CAP) {
        for (int i = tid; i < tot; i += BLKP) {
            int rec = tmp[S + i];
            int nl = rec & 511;
            int slot = ofs[nl] + atomicAdd(&fill[nl], 1);
            stage[slot] = rec >> 9;
        }
        __syncthreads();
        for (int i = tid; i < tot; i += BLKP) psrc[S + i] = stage[i];
    } else {
        for (int i = tid; i < tot; i += BLKP) {
            int rec = tmp[S + i];
            int nl = rec & 511;
            int slot = S + ofs[nl] + atomicAdd(&fill[nl], 1);
            psrc[slot] = rec >> 9;
        }
    }
}

// U0[n] = dis[n]*x[n], bf16 64B rows (4 x uint4)
__global__ void cvt_u0_kernel(const float* __restrict__ x, const float* __restrict__ dis,
                              uint4* __restrict__ u0, int N) {
    int t = blockIdx.x * blockDim.x + threadIdx.x;  // one 16B chunk (8 feats)
    if (t >= N * 4) return;
    int n = t >> 2;
    int c = t & 3;
    float dn = dis[n];
    const float4* in4 = reinterpret_cast<const float4*>(x + (size_t)n * 32 + c * 8);
    float4 a = in4[0], b = in4[1];
    float r[8] = {dn * a.x, dn * a.y, dn * a.z, dn * a.w,
                  dn * b.x, dn * b.y, dn * b.z, dn * b.w};
    u0[(size_t)n * 4 + c] = pack8(r);
}

// ---------- U-space props: pure gather-sum, epilogue *(-scale*d2[n]) - prevU ----
// F=32: 64B rows (4 chunks), 4 lanes/node. F=16: 32B rows (2 chunks), 2 lanes/node.
template <int C, bool HAVE_PREV>   // C = chunks per row (4 or 2)
__global__ void prop_u_kernel(const int* __restrict__ rowptr, const int* __restrict__ psrc,
                              const float* __restrict__ d2, const uint4* __restrict__ vb,
                              const uint4* __restrict__ prevb, uint4* __restrict__ outb,
                              float scale, int N) {
    int t = blockIdx.x * blockDim.x + threadIdx.x;
    int n = t / C;
    int c = t % C;
    if (n >= N) return;
    int beg = rowptr[n];
    int end = rowptr[n + 1];
    float acc[8];
#pragma unroll
    for (int j = 0; j < 8; j++) acc[j] = 0.f;
    int i = beg;
    for (; i + 3 < end; i += 4) {
        int s0 = psrc[i], s1 = psrc[i + 1], s2 = psrc[i + 2], s3 = psrc[i + 3];
        uint4 a0 = vb[(size_t)s0 * C + c];
        uint4 a1 = vb[(size_t)s1 * C + c];
        uint4 a2 = vb[(size_t)s2 * C + c];
        uint4 a3 = vb[(size_t)s3 * C + c];
        add8(a0, acc);
        add8(a1, acc);
        add8(a2, acc);
        add8(a3, acc);
    }
    for (; i < end; i++) {
        uint4 a0 = vb[(size_t)psrc[i] * C + c];
        add8(a0, acc);
    }
    float f = -scale * d2[n];
    float r[8];
    if (HAVE_PREV) {
        float p[8];
        unpack8(prevb[(size_t)n * C + c], p);
#pragma unroll
        for (int j = 0; j < 8; j++) r[j] = f * acc[j] - p[j];
    } else {
#pragma unroll
        for (int j = 0; j < 8; j++) r[j] = f * acc[j];
    }
    outb[(size_t)n * C + c] = pack8(r);
}

// h = relu(b1 + x@W1[0] + sum_{k=1..3} (Uk*inv)@W1[k]); deg-0: Tx2=-x.
// writes hb (plain bf16 h, 32B row) and uh (dis*h, the layer-2 gather table)
__global__ void combine1_kernel(const float* __restrict__ x, const uint4* __restrict__ u1,
                                const uint4* __restrict__ u2, const uint4* __restrict__ u3,
                                const float* __restrict__ inv, const float* __restrict__ dis,
                                const float* __restrict__ W1, const float* __restrict__ b1,
                                uint4* __restrict__ hb, uint4* __restrict__ uh, int N) {
    __shared__ float sW[4 * 32 * 16];
    __shared__ float sb[16];
    for (int i = threadIdx.x; i < 4 * 32 * 16; i += blockDim.x) sW[i] = W1[i];
    if (threadIdx.x < 16) sb[threadIdx.x] = b1[threadIdx.x];
    __syncthreads();
    int n = blockIdx.x * blockDim.x + threadIdx.x;
    if (n >= N) return;
    float acc[16];
#pragma unroll
    for (int j = 0; j < 16; j++) acc[j] = sb[j];
    float iv = inv[n];
    float xrow[32];
    {
        const float4* in4 = reinterpret_cast<const float4*>(x + (size_t)n * 32);
#pragma unroll
        for (int q = 0; q < 8; q++) {
            float4 a = in4[q];
            xrow[q * 4 + 0] = a.x; xrow[q * 4 + 1] = a.y;
            xrow[q * 4 + 2] = a.z; xrow[q * 4 + 3] = a.w;
        }
#pragma unroll
        for (int i = 0; i < 32; i++) {
            float xv = xrow[i];
#pragma unroll
            for (int j = 0; j < 16; j++) acc[j] += xv * sW[i * 16 + j];
        }
    }
    const uint4* tabs[3] = {u1, u2, u3};
#pragma unroll
    for (int k = 0; k < 3; k++) {
        float row[32];
#pragma unroll
        for (int c = 0; c < 4; c++) unpack8(tabs[k][(size_t)n * 4 + c], row + c * 8);
        const float* Wk = sW + (k + 1) * 512;
#pragma unroll
        for (int i = 0; i < 32; i++) {
            float xv = row[i] * iv;
#pragma unroll
            for (int j = 0; j < 16; j++) acc[j] += xv * Wk[i * 16 + j];
        }
    }
    if (iv == 0.0f) {  // deg-0: Tx2 = -x (U-space lost it); Tx1=Tx3=0 already
        const float* W2k = sW + 2 * 512;
#pragma unroll
        for (int i = 0; i < 32; i++) {
            float xv = -xrow[i];
#pragma unroll
            for (int j = 0; j < 16; j++) acc[j] += xv * W2k[i * 16 + j];
        }
    }
    float dn = dis[n];
    float r[16], u[16];
#pragma unroll
    for (int j = 0; j < 16; j++) {
        r[j] = fmaxf(acc[j], 0.0f);
        u[j] = dn * r[j];
    }
    hb[(size_t)n * 2 + 0] = pack8(r);
    hb[(size_t)n * 2 + 1] = pack8(r + 8);
    uh[(size_t)n * 2 + 0] = pack8(u);
    uh[(size_t)n * 2 + 1] = pack8(u + 8);
}

// o = log_softmax(b2 + h@W2[0] + sum_k (USk*inv)@W2[k]); deg-0: S2=-h.
__global__ void combine2_kernel(const uint4* __restrict__ hb, const uint4* __restrict__ us1,
                                const uint4* __restrict__ us2, const uint4* __restrict__ us3,
                                const float* __restrict__ inv,
                                const float* __restrict__ W2, const float* __restrict__ b2,
                                float* __restrict__ out, int N) {
    __shared__ float sW[4 * 16 * 10];
    __shared__ float sb[10];
    for (int i = threadIdx.x; i < 4 * 16 * 10; i += blockDim.x) sW[i] = W2[i];
    if (threadIdx.x < 10) sb[threadIdx.x] = b2[threadIdx.x];
    __syncthreads();
    int n = blockIdx.x * blockDim.x + threadIdx.x;
    if (n >= N) return;
    float acc[10];
#pragma unroll
    for (int c = 0; c < 10; c++) acc[c] = sb[c];
    float iv = inv[n];
    float hrow[16];
    unpack8(hb[(size_t)n * 2 + 0], hrow + 0);
    unpack8(hb[(size_t)n * 2 + 1], hrow + 8);
#pragma unroll
    for (int i = 0; i < 16; i++) {
        float xv = hrow[i];
#pragma unroll
        for (int c = 0; c < 10; c++) acc[c] += xv * sW[i * 10 + c];
    }
    const uint4* tabs[3] = {us1, us2, us3};
#pragma unroll
    for (int k = 0; k < 3; k++) {
        float row[16];
        unpack8(tabs[k][(size_t)n * 2 + 0], row + 0);
        unpack8(tabs[k][(size_t)n * 2 + 1], row + 8);
        const float* Wk = sW + (k + 1) * 160;
#pragma unroll
        for (int i = 0; i < 16; i++) {
            float xv = row[i] * iv;
#pragma unroll
            for (int c = 0; c < 10; c++) acc[c] += xv * Wk[i * 10 + c];
        }
    }
    if (iv == 0.0f) {  // deg-0: S2 = -h
        const float* W2k = sW + 2 * 160;
#pragma unroll
        for (int i = 0; i < 16; i++) {
            float xv = -hrow[i];
#pragma unroll
            for (int c = 0; c < 10; c++) acc[c] += xv * W2k[i * 10 + c];
        }
    }
    float m = acc[0];
#pragma unroll
    for (int c = 1; c < 10; c++) m = fmaxf(m, acc[c]);
    float sum = 0.0f;
#pragma unroll
    for (int c = 0; c < 10; c++) sum += expf(acc[c] - m);
    float lse = m + logf(sum);
    float* o = out + (size_t)n * 10;
#pragma unroll
    for (int c = 0; c < 10; c++) o[c] = acc[c] - lse;
}

extern "C" void kernel_launch(void* const* d_in, const int* in_sizes, int n_in,
                              void* d_out, int out_size, void* d_ws, size_t ws_size,
                              hipStream_t stream) {
    const float* x  = (const float*)d_in[0];
    const int*   ei = (const int*)d_in[1];
    const float* W1 = (const float*)d_in[2];
    const float* b1 = (const float*)d_in[3];
    const float* W2 = (const float*)d_in[4];
    const float* b2 = (const float*)d_in[5];
    float* out = (float*)d_out;

    const int N = in_sizes[0] / 32;   // 100000
    const int E = in_sizes[1] / 2;    // 1600000
    const int* src = ei;
    const int* dst = ei + E;

    const int nbuck = (N + 511) / 512;        // 196

    // workspace layout (16B-aligned regions)
    char* w = (char*)d_ws;
    int*   bcnt   = (int*)w;              w += NBUCK_MAX * 4;
    int*   bbase  = (int*)w;              w += (NBUCK_MAX + 4) * 4;
    int*   bfill  = (int*)w;              w += NBUCK_MAX * 4;
    int*   rowptr = (int*)w;              w += (size_t)(N + 4) * 4;
    float* dis    = (float*)w;            w += (size_t)N * 4;
    float* d2     = (float*)w;            w += (size_t)N * 4;
    float* inv    = (float*)w;            w += (size_t)N * 4;
    int*   tmp    = (int*)w;              w += (size_t)E * 4;
    int*   psrc   = (int*)w;              w += (size_t)E * 4;
    uint4* u0     = (uint4*)w;            w += (size_t)64 * N;   // 32 bf16 = 64B rows
    uint4* u1     = (uint4*)w;            w += (size_t)64 * N;
    uint4* u2     = (uint4*)w;            w += (size_t)64 * N;
    uint4* u3     = (uint4*)w;            w += (size_t)64 * N;
    uint4* hb     = (uint4*)w;            w += (size_t)32 * N;   // 16 bf16 = 32B rows
    uint4* uh     = (uint4*)w;            w += (size_t)32 * N;
    uint4* us1    = (uint4*)w;            w += (size_t)32 * N;
    uint4* us2    = (uint4*)w;            w += (size_t)32 * N;
    uint4* us3    = (uint4*)w;            w += (size_t)32 * N;

    int gN   = (N + BLK - 1) / BLK;
    int gU32 = (N * 4 + BLK - 1) / BLK;   // 4 lanes/node
    int gU16 = (N * 2 + BLK - 1) / BLK;   // 2 lanes/node
    int gCH  = (E + CHUNK - 1) / CHUNK;

    // ---- CSR build ----
    hipMemsetAsync(bcnt, 0, NBUCK_MAX * sizeof(int), stream);
    bucket_count_kernel<<<1024, BLK, 0, stream>>>(dst, bcnt, E, nbuck);
    bucket_scan_kernel<<<1, BLK, 0, stream>>>(bcnt, bbase, bfill, rowptr, nbuck, N, E);
    binned_scatter_kernel<<<gCH, BLK, 0, stream>>>(src, dst, bbase, bfill, tmp, E, nbuck);
    bucket_place_kernel<<<nbuck, BLKP, 0, stream>>>(bbase, tmp, psrc, rowptr, dis, d2, inv, N);

    // ---- layer 1 (F=32, bf16 U-tables, 64B rows) ----
    cvt_u0_kernel<<<gU32, BLK, 0, stream>>>(x, dis, u0, N);
    prop_u_kernel<4, false><<<gU32, BLK, 0, stream>>>(rowptr, psrc, d2, u0, nullptr, u1, 1.0f, N);
    prop_u_kernel<4, true ><<<gU32, BLK, 0, stream>>>(rowptr, psrc, d2, u1, u0,      u2, 2.0f, N);
    prop_u_kernel<4, true ><<<gU32, BLK, 0, stream>>>(rowptr, psrc, d2, u2, u1,      u3, 2.0f, N);
    combine1_kernel<<<gN, BLK, 0, stream>>>(x, u1, u2, u3, inv, dis, W1, b1, hb, uh, N);

    // ---- layer 2 (F=16, bf16 U-tables, 32B rows) ----
    prop_u_kernel<2, false><<<gU16, BLK, 0, stream>>>(rowptr, psrc, d2, uh,  nullptr, us1, 1.0f, N);
    prop_u_kernel<2, true ><<<gU16, BLK, 0, stream>>>(rowptr, psrc, d2, us1, uh,      us2, 2.0f, N);
    prop_u_kernel<2, true ><<<gU16, BLK, 0, stream>>>(rowptr, psrc, d2, us2, us1,     us3, 2.0f, N);
    combine2_kernel<<<gN, BLK, 0, stream>>>(hb, us1, us2, us3, inv, W2, b2, out, N);
}